// Round 26
// baseline (231.922 us; speedup 1.0000x reference)
//
#include <hip/hip_runtime.h>
#include <hip/hip_bf16.h>
#include <cstddef>

#define BN 4096
#define DD 128
#define NSTEPS 100
#define PTILE 128
#define PLSTR 136   // phase-2 padded LDS row stride (bf16 elems)
#define GRID_T 32
#define NOFF 496    // strictly-upper tile pairs (ti<tj)
#define NBLK2 512   // 496 off-diag + 16 blocks x 2 diagonal tiles
#define NREPH 16    // phase-2 hist replicas (stride 101)
#define NREPC2 8    // phase-3 cdf float2 replicas (stride 101)

typedef __attribute__((ext_vector_type(8))) short bf16x8;
typedef __attribute__((ext_vector_type(4))) float f32x4;

__device__ __forceinline__ void faddf(float* p, float v) { unsafeAtomicAdd(p, v); }

// Manual grid barrier: all NBLK2 blocks are co-resident (LDS 72KB -> 2/CU,
// grid = 2*256). threadfence release/acquire gives cross-XCD visibility
// (wbl2 on release, inv on acquire) per G16.
__device__ __forceinline__ void gridbar(unsigned int* ctr, unsigned int target) {
    __threadfence();
    __syncthreads();
    if (threadIdx.x == 0) {
        __hip_atomic_fetch_add(ctr, 1u, __ATOMIC_ACQ_REL, __HIP_MEMORY_SCOPE_AGENT);
        while (__hip_atomic_load(ctr, __ATOMIC_ACQUIRE, __HIP_MEMORY_SCOPE_AGENT) < target)
            __builtin_amdgcn_s_sleep(8);
    }
    __syncthreads();
    __threadfence();
}

// ctl layout: gPos[100] gLoss[32] gCnt[32] gDone bar1 bar2  (167 words, memset 0)
__global__ __launch_bounds__(256, 2) void hl_fused(const float* __restrict__ emb,
                                                   const int* __restrict__ cls,
                                                   ushort* __restrict__ nemb,
                                                   float* __restrict__ gPos,
                                                   float* __restrict__ gLoss,
                                                   float* __restrict__ gCnt,
                                                   unsigned int* __restrict__ gDone,
                                                   unsigned int* __restrict__ gBar1,
                                                   unsigned int* __restrict__ gBar2,
                                                   float* __restrict__ out) {
    __shared__ __align__(16) char arena[65536];   // ph2 scratch / ph3 A,B tiles
    ushort* As = (ushort*)arena;                  // ph3: 32768 B
    ushort* Bs = (ushort*)(arena + 32768);        // ph3: 32768 B
    int* p2idx = (int*)arena;                     // ph2: 1024 B
    int* p2scan = (int*)(arena + 1024);           // ph2: 1024 B
    float* p2hist = (float*)(arena + 2048);       // ph2: 6464 B
    ushort* p2As = (ushort*)(arena + 8512);       // ph2: 17408 B (16B-aligned)
    ushort* p2Bs = (ushort*)(arena + 25920);      // ph2: 17408 B
    __shared__ float2 cdf2[NREPC2 * 101];         // 6464 B
    __shared__ float scanbuf[128];
    __shared__ float red[8];
    __shared__ int clsA[PTILE], clsB[PTILE];
    __shared__ int mTot;

    const int tid = threadIdx.x;
    const int bid = blockIdx.x;
    const int lane = tid & 63;
    const int wid = tid >> 6;

    constexpr float STEPF = 2.0f / 99.0f;
    constexpr float INVSTEP = 49.5f;
    constexpr float CLIPV = 1.0f - 1e-6f;
    (void)STEPF;

    // ================= Phase 1: normalize 8 rows/block -> nemb =================
    #pragma unroll
    for (int rr = 0; rr < 2; ++rr) {
        int row = bid * 8 + wid * 2 + rr;
        const float2 v = *(const float2*)(emb + (size_t)row * DD + 2 * lane);
        float ss = v.x * v.x + v.y * v.y;
        #pragma unroll
        for (int off = 32; off > 0; off >>= 1) ss += __shfl_xor(ss, off);
        float inv = 1.0f / sqrtf(ss);
        __hip_bfloat16 b0 = __float2bfloat16(v.x * inv);
        __hip_bfloat16 b1 = __float2bfloat16(v.y * inv);
        ushort2 pk;
        pk.x = *(ushort*)&b0;
        pk.y = *(ushort*)&b1;
        *(ushort2*)(nemb + (size_t)row * DD + 2 * lane) = pk;
    }

    gridbar(gBar1, NBLK2);

    // ================= Phase 2 (blocks 0..99): POS hist via MFMA gram ==========
    if (bid < NSTEPS) {
        const int c = bid;
        for (int i = tid; i < NREPH * 101; i += 256) p2hist[i] = 0.f;

        const int base = tid * 16;
        int myCnt = 0;
        #pragma unroll
        for (int k = 0; k < 16; ++k) myCnt += (cls[base + k] == c);
        p2scan[tid] = myCnt;
        __syncthreads();
        for (int s = 1; s < 256; s <<= 1) {
            int v = (tid >= s) ? p2scan[tid - s] : 0;
            __syncthreads();
            p2scan[tid] += v;
            __syncthreads();
        }
        int w = p2scan[tid] - myCnt;
        if (tid == 255) mTot = p2scan[255] > 256 ? 256 : p2scan[255];
        #pragma unroll
        for (int k = 0; k < 16; ++k) {
            if (cls[base + k] == c && w < 256) { p2idx[w] = base + k; ++w; }
        }
        __syncthreads();
        const int m = mTot;
        const int nt = (m + 63) >> 6;

        const int wv = wid;
        const int lr = lane & 15;
        const int kg = lane >> 4;
        const int rep = (lane & 15) * 101;

        for (int si = 0; si < nt; ++si) {
            for (int sj = si; sj < nt; ++sj) {
                __syncthreads();
                #pragma unroll
                for (int it = 0; it < 4; ++it) {
                    int q = it * 256 + tid;
                    int row = q >> 4;
                    int ch = q & 15;
                    int ga = si * 64 + row;
                    int gb = sj * 64 + row;
                    int ra = p2idx[ga < m ? ga : 0];
                    int rb = p2idx[gb < m ? gb : 0];
                    *(float4*)(&p2As[row * PLSTR + ch * 8]) =
                        *(const float4*)(nemb + (size_t)ra * DD + ch * 8);
                    *(float4*)(&p2Bs[row * PLSTR + ch * 8]) =
                        *(const float4*)(nemb + (size_t)rb * DD + ch * 8);
                }
                __syncthreads();

                f32x4 zero4 = {0.f, 0.f, 0.f, 0.f};
                f32x4 pacc[4] = {zero4, zero4, zero4, zero4};
                #pragma unroll
                for (int ks = 0; ks < 4; ++ks) {
                    bf16x8 af = *(const bf16x8*)(&p2As[(wv * 16 + lr) * PLSTR + ks * 32 + kg * 8]);
                    #pragma unroll
                    for (int fb = 0; fb < 4; ++fb) {
                        bf16x8 bf = *(const bf16x8*)(&p2Bs[(fb * 16 + lr) * PLSTR + ks * 32 + kg * 8]);
                        pacc[fb] = __builtin_amdgcn_mfma_f32_16x16x32_bf16(af, bf, pacc[fb], 0, 0, 0);
                    }
                }

                #pragma unroll
                for (int fb = 0; fb < 4; ++fb) {
                    const int gb = sj * 64 + fb * 16 + lr;
                    #pragma unroll
                    for (int j = 0; j < 4; ++j) {
                        const int ga = si * 64 + wv * 16 + kg * 4 + j;
                        if (ga < gb && gb < m) {
                            float s = pacc[fb][j];
                            s = fminf(fmaxf(s, -CLIPV), CLIPV);
                            float u = (s + CLIPV) * INVSTEP;
                            int jb = (int)u;
                            if (jb > 98) jb = 98;
                            float w_hi = u - (float)jb;
                            float w_lo = 1.0f - w_hi;
                            faddf(&p2hist[rep + jb], w_lo);
                            faddf(&p2hist[rep + jb + 1], w_hi);
                        }
                    }
                }
            }
        }
        __syncthreads();
        if (tid < NSTEPS) {
            float v = 0.f;
            #pragma unroll
            for (int r = 0; r < NREPH; ++r) v += p2hist[r * 101 + tid];
            if (v != 0.f) faddf(&gPos[tid], v);
        }
    }

    gridbar(gBar2, NBLK2);

    // ================= Phase 3: NEG GEMM + cdf gather =================
    // local cdf: scan gPos, store float2{cdf, delta} replicas
    if (tid < 128) scanbuf[tid] = (tid < NSTEPS) ? gPos[tid] : 0.f;
    __syncthreads();
    for (int off = 1; off < 128; off <<= 1) {
        float v = 0.f;
        if (tid < 128 && tid >= off) v = scanbuf[tid - off];
        __syncthreads();
        if (tid < 128) scanbuf[tid] += v;
        __syncthreads();
    }
    const float invsp = 1.0f / scanbuf[NSTEPS - 1];
    for (int i = tid; i < NREPC2 * NSTEPS; i += 256) {
        int r = i / NSTEPS, b = i - r * NSTEPS;
        float c0 = scanbuf[b] * invsp;
        float c1 = ((b < NSTEPS - 1) ? scanbuf[b + 1] : scanbuf[NSTEPS - 1]) * invsp;
        float2 cd; cd.x = c0; cd.y = c1 - c0;
        cdf2[r * 101 + b] = cd;
    }

    // unit decode
    int ti0, tj0, ti1 = 0, nu = 1;
    {
        int t = bid;
        if (t < NOFF) {
            int ti = 0, rem = t;
            while (rem >= GRID_T - 1 - ti) { rem -= GRID_T - 1 - ti; ++ti; }
            ti0 = ti; tj0 = ti + 1 + rem;
        } else {
            int d = (t - NOFF) * 2;
            ti0 = tj0 = d; ti1 = d + 1; nu = 2;
        }
    }

    const int wr = wid >> 1, wc = wid & 1;
    const int lr = lane & 15;
    const int kg = lane >> 4;
    const float2* crep2 = &cdf2[(lane & 7) * 101];
    const int li_base = wr * 64 + (kg << 2);
    const int lj_base = wc * 64 + lr;

    float lacc = 0.f, lcnt = 0.f;
    const int rloc = lane >> 4;
    const int pch = lane & 15;

    for (int u = 0; u < nu; ++u) {
        const int ti = u ? ti1 : ti0;
        const int tj = u ? ti1 : tj0;
        const bool diag = (ti == tj);

        __syncthreads();
        if (tid < PTILE) clsA[tid] = cls[ti * PTILE + tid];
        else             clsB[tid - PTILE] = cls[tj * PTILE + (tid - PTILE)];

        {
            const ushort* Ag = nemb + (size_t)(ti * PTILE) * DD;
            const ushort* Bg = nemb + (size_t)(tj * PTILE) * DD;
            #pragma unroll
            for (int t = 0; t < 8; ++t) {
                int row = wid * 32 + t * 4 + rloc;
                int lch = pch ^ (row & 7);
                const ushort* ga = Ag + (size_t)row * DD + lch * 8;
                ushort* la = &As[(wid * 32 + t * 4) * 128];
                __builtin_amdgcn_global_load_lds(
                    (const __attribute__((address_space(1))) void*)ga,
                    (__attribute__((address_space(3))) void*)la, 16, 0, 0);
            }
            if (!diag) {
                #pragma unroll
                for (int t = 0; t < 8; ++t) {
                    int row = wid * 32 + t * 4 + rloc;
                    int lch = pch ^ (row & 7);
                    const ushort* gb = Bg + (size_t)row * DD + lch * 8;
                    ushort* lb = &Bs[(wid * 32 + t * 4) * 128];
                    __builtin_amdgcn_global_load_lds(
                        (const __attribute__((address_space(1))) void*)gb,
                        (__attribute__((address_space(3))) void*)lb, 16, 0, 0);
                }
            }
        }
        __syncthreads();

        const ushort* Bsel = diag ? As : Bs;
        const int* clsBsel = diag ? clsA : clsB;

        f32x4 zero4 = {0.f, 0.f, 0.f, 0.f};
        f32x4 acc[4][4];
        #pragma unroll
        for (int a = 0; a < 4; ++a)
            #pragma unroll
            for (int b = 0; b < 4; ++b) acc[a][b] = zero4;

        #pragma unroll
        for (int ks = 0; ks < 4; ++ks) {
            bf16x8 af[4], bfr[4];
            #pragma unroll
            for (int f = 0; f < 4; ++f) {
                int arow = wr * 64 + f * 16 + lr;
                int pca = ((ks << 2) | kg) ^ (arow & 7);
                af[f] = *(const bf16x8*)(&As[arow * 128 + pca * 8]);
                int brow = wc * 64 + f * 16 + lr;
                int pcb = ((ks << 2) | kg) ^ (brow & 7);
                bfr[f] = *(const bf16x8*)(&Bsel[brow * 128 + pcb * 8]);
            }
            #pragma unroll
            for (int fa = 0; fa < 4; ++fa)
                #pragma unroll
                for (int fb = 0; fb < 4; ++fb)
                    acc[fa][fb] = __builtin_amdgcn_mfma_f32_16x16x32_bf16(af[fa], bfr[fb], acc[fa][fb], 0, 0, 0);
        }

        int ca[16];
        #pragma unroll
        for (int fa = 0; fa < 4; ++fa)
            #pragma unroll
            for (int j = 0; j < 4; ++j) ca[fa * 4 + j] = clsA[li_base + fa * 16 + j];

        const bool offdiag = !diag;
        #pragma unroll
        for (int fb = 0; fb < 4; ++fb) {
            const int lj = lj_base + fb * 16;
            const int cb = clsBsel[lj];
            #pragma unroll
            for (int fa = 0; fa < 4; ++fa) {
                const int li0 = li_base + fa * 16;
                f32x4 v = acc[fa][fb];
                #pragma unroll
                for (int j = 0; j < 4; ++j) {
                    const int li = li0 + j;
                    const bool mneg = (offdiag || (li < lj)) && (ca[fa * 4 + j] != cb);
                    float s = v[j];
                    s = fminf(fmaxf(s, -CLIPV), CLIPV);
                    float uu = (s + CLIPV) * INVSTEP;
                    int jb = (int)uu;
                    if (jb > 98) jb = 98;
                    float w_hi = uu - (float)jb;          // == (s - t_j)*INVSTEP
                    float2 cd = crep2[jb];                // one ds_read_b64
                    float mm = mneg ? 1.0f : 0.0f;
                    lacc = fmaf(mm, fmaf(w_hi, cd.y, cd.x), lacc);
                    lcnt += mm;
                }
            }
        }
    }

    // reduce + final
    #pragma unroll
    for (int off = 32; off > 0; off >>= 1) {
        lacc += __shfl_xor(lacc, off);
        lcnt += __shfl_xor(lcnt, off);
    }
    if (lane == 0) { red[wid] = lacc; red[4 + wid] = lcnt; }
    __syncthreads();
    if (tid == 0) {
        float L = red[0] + red[1] + red[2] + red[3];
        float C = red[4] + red[5] + red[6] + red[7];
        faddf(&gLoss[bid & 31], L);
        faddf(&gCnt[bid & 31], C);
        __threadfence();
        unsigned int tk = atomicAdd(gDone, 1u);
        if (tk == NBLK2 - 1) {
            __threadfence();
            float ls = 0.f, cs = 0.f;
            for (int i = 0; i < 32; ++i) {
                ls += __hip_atomic_load(&gLoss[i], __ATOMIC_RELAXED, __HIP_MEMORY_SCOPE_AGENT);
                cs += __hip_atomic_load(&gCnt[i], __ATOMIC_RELAXED, __HIP_MEMORY_SCOPE_AGENT);
            }
            out[0] = ls / cs;            // cdf already contains 1/sp
        }
    }
}

extern "C" void kernel_launch(void* const* d_in, const int* in_sizes, int n_in,
                              void* d_out, int out_size, void* d_ws, size_t ws_size,
                              hipStream_t stream) {
    const float* emb = (const float*)d_in[0];
    const int* classes = (const int*)d_in[1];
    float* out = (float*)d_out;

    ushort* nemb = (ushort*)d_ws;                                   // 1 MB
    float* ctl = (float*)((char*)d_ws + (size_t)BN * DD * sizeof(ushort));
    float* gPos = ctl;                                  // 100
    float* gLoss = gPos + NSTEPS;                       // 32
    float* gCnt = gLoss + 32;                           // 32
    unsigned int* gDone = (unsigned int*)(gCnt + 32);   // 1
    unsigned int* gBar1 = gDone + 1;                    // 1
    unsigned int* gBar2 = gBar1 + 1;                    // 1

    hipMemsetAsync(ctl, 0, 167 * sizeof(float), stream);
    hl_fused<<<NBLK2, 256, 0, stream>>>(emb, classes, nemb, gPos, gLoss, gCnt,
                                        gDone, gBar1, gBar2, out);
}

// Round 27
// 121.794 us; speedup vs baseline: 1.9042x; 1.9042x over previous
//
#include <hip/hip_runtime.h>
#include <hip/hip_bf16.h>
#include <cstddef>

#define BN 4096
#define DD 128
#define NSTEPS 100
#define PTILE 128
#define PLSTR 136   // phase-2 padded LDS row stride (bf16 elems)
#define GRID_T 32
#define NOFF 496    // strictly-upper tile pairs (ti<tj)
#define NBLK2 512   // 496 off-diag + 16 blocks x 2 diagonal tiles
#define NREPH 16    // phase-2 hist replicas (stride 101)
#define NREPC2 8    // phase-3 cdf float2 replicas (stride 101)

typedef __attribute__((ext_vector_type(8))) short bf16x8;
typedef __attribute__((ext_vector_type(4))) float f32x4;

__device__ __forceinline__ void faddf(float* p, float v) { unsafeAtomicAdd(p, v); }

// Manual grid barrier, r27 fix: spin on RELAXED atomic fetch_add(0) — RMWs
// execute at the coherent point and see progress WITHOUT the per-iteration
// cache invalidate that ACQUIRE loads emit (r26: ~500 spinners x invalidate
// every 0.2us = permanently cold L2 = 217us). One threadfence after exit
// gives the acquire; arrival keeps release fence + add.
__device__ __forceinline__ void gridbar(unsigned int* ctr, unsigned int target) {
    __syncthreads();
    if (threadIdx.x == 0) {
        __threadfence();   // release this block's writes
        __hip_atomic_fetch_add(ctr, 1u, __ATOMIC_RELAXED, __HIP_MEMORY_SCOPE_AGENT);
        while (__hip_atomic_fetch_add(ctr, 0u, __ATOMIC_RELAXED, __HIP_MEMORY_SCOPE_AGENT) < target)
            __builtin_amdgcn_s_sleep(32);   // ~2048 cyc between probes
        __threadfence();   // acquire other blocks' writes
    }
    __syncthreads();
}

// ctl layout: gPos[100] gLoss[32] gCnt[32] gDone bar1 bar2  (167 words, memset 0)
__global__ __launch_bounds__(256, 2) void hl_fused(const float* __restrict__ emb,
                                                   const int* __restrict__ cls,
                                                   ushort* __restrict__ nemb,
                                                   float* __restrict__ gPos,
                                                   float* __restrict__ gLoss,
                                                   float* __restrict__ gCnt,
                                                   unsigned int* __restrict__ gDone,
                                                   unsigned int* __restrict__ gBar1,
                                                   unsigned int* __restrict__ gBar2,
                                                   float* __restrict__ out) {
    __shared__ __align__(16) char arena[65536];   // ph2 scratch / ph3 A,B tiles
    ushort* As = (ushort*)arena;                  // ph3: 32768 B
    ushort* Bs = (ushort*)(arena + 32768);        // ph3: 32768 B
    int* p2idx = (int*)arena;                     // ph2: 1024 B
    int* p2scan = (int*)(arena + 1024);           // ph2: 1024 B
    float* p2hist = (float*)(arena + 2048);       // ph2: 6464 B
    ushort* p2As = (ushort*)(arena + 8512);       // ph2: 17408 B (16B-aligned)
    ushort* p2Bs = (ushort*)(arena + 25920);      // ph2: 17408 B
    __shared__ float2 cdf2[NREPC2 * 101];         // 6464 B
    __shared__ float scanbuf[128];
    __shared__ float red[8];
    __shared__ int clsA[PTILE], clsB[PTILE];
    __shared__ int mTot;

    const int tid = threadIdx.x;
    const int bid = blockIdx.x;
    const int lane = tid & 63;
    const int wid = tid >> 6;

    constexpr float INVSTEP = 49.5f;
    constexpr float CLIPV = 1.0f - 1e-6f;

    // ================= Phase 1: normalize 8 rows/block -> nemb =================
    #pragma unroll
    for (int rr = 0; rr < 2; ++rr) {
        int row = bid * 8 + wid * 2 + rr;
        const float2 v = *(const float2*)(emb + (size_t)row * DD + 2 * lane);
        float ss = v.x * v.x + v.y * v.y;
        #pragma unroll
        for (int off = 32; off > 0; off >>= 1) ss += __shfl_xor(ss, off);
        float inv = 1.0f / sqrtf(ss);
        __hip_bfloat16 b0 = __float2bfloat16(v.x * inv);
        __hip_bfloat16 b1 = __float2bfloat16(v.y * inv);
        ushort2 pk;
        pk.x = *(ushort*)&b0;
        pk.y = *(ushort*)&b1;
        *(ushort2*)(nemb + (size_t)row * DD + 2 * lane) = pk;
    }

    gridbar(gBar1, NBLK2);

    // ================= Phase 2 (blocks 0..99): POS hist via MFMA gram ==========
    if (bid < NSTEPS) {
        const int c = bid;
        for (int i = tid; i < NREPH * 101; i += 256) p2hist[i] = 0.f;

        const int base = tid * 16;
        int myCnt = 0;
        #pragma unroll
        for (int k = 0; k < 16; ++k) myCnt += (cls[base + k] == c);
        p2scan[tid] = myCnt;
        __syncthreads();
        for (int s = 1; s < 256; s <<= 1) {
            int v = (tid >= s) ? p2scan[tid - s] : 0;
            __syncthreads();
            p2scan[tid] += v;
            __syncthreads();
        }
        int w = p2scan[tid] - myCnt;
        if (tid == 255) mTot = p2scan[255] > 256 ? 256 : p2scan[255];
        #pragma unroll
        for (int k = 0; k < 16; ++k) {
            if (cls[base + k] == c && w < 256) { p2idx[w] = base + k; ++w; }
        }
        __syncthreads();
        const int m = mTot;
        const int nt = (m + 63) >> 6;

        const int wv = wid;
        const int lr = lane & 15;
        const int kg = lane >> 4;
        const int rep = (lane & 15) * 101;

        for (int si = 0; si < nt; ++si) {
            for (int sj = si; sj < nt; ++sj) {
                __syncthreads();
                #pragma unroll
                for (int it = 0; it < 4; ++it) {
                    int q = it * 256 + tid;
                    int row = q >> 4;
                    int ch = q & 15;
                    int ga = si * 64 + row;
                    int gb = sj * 64 + row;
                    int ra = p2idx[ga < m ? ga : 0];
                    int rb = p2idx[gb < m ? gb : 0];
                    *(float4*)(&p2As[row * PLSTR + ch * 8]) =
                        *(const float4*)(nemb + (size_t)ra * DD + ch * 8);
                    *(float4*)(&p2Bs[row * PLSTR + ch * 8]) =
                        *(const float4*)(nemb + (size_t)rb * DD + ch * 8);
                }
                __syncthreads();

                f32x4 zero4 = {0.f, 0.f, 0.f, 0.f};
                f32x4 pacc[4] = {zero4, zero4, zero4, zero4};
                #pragma unroll
                for (int ks = 0; ks < 4; ++ks) {
                    bf16x8 af = *(const bf16x8*)(&p2As[(wv * 16 + lr) * PLSTR + ks * 32 + kg * 8]);
                    #pragma unroll
                    for (int fb = 0; fb < 4; ++fb) {
                        bf16x8 bf = *(const bf16x8*)(&p2Bs[(fb * 16 + lr) * PLSTR + ks * 32 + kg * 8]);
                        pacc[fb] = __builtin_amdgcn_mfma_f32_16x16x32_bf16(af, bf, pacc[fb], 0, 0, 0);
                    }
                }

                #pragma unroll
                for (int fb = 0; fb < 4; ++fb) {
                    const int gb = sj * 64 + fb * 16 + lr;
                    #pragma unroll
                    for (int j = 0; j < 4; ++j) {
                        const int ga = si * 64 + wv * 16 + kg * 4 + j;
                        if (ga < gb && gb < m) {
                            float s = pacc[fb][j];
                            s = fminf(fmaxf(s, -CLIPV), CLIPV);
                            float u = (s + CLIPV) * INVSTEP;
                            int jb = (int)u;
                            if (jb > 98) jb = 98;
                            float w_hi = u - (float)jb;
                            float w_lo = 1.0f - w_hi;
                            faddf(&p2hist[rep + jb], w_lo);
                            faddf(&p2hist[rep + jb + 1], w_hi);
                        }
                    }
                }
            }
        }
        __syncthreads();
        if (tid < NSTEPS) {
            float v = 0.f;
            #pragma unroll
            for (int r = 0; r < NREPH; ++r) v += p2hist[r * 101 + tid];
            if (v != 0.f) faddf(&gPos[tid], v);
        }
    }

    gridbar(gBar2, NBLK2);

    // ================= Phase 3: NEG GEMM + cdf gather =================
    if (tid < 128) scanbuf[tid] = (tid < NSTEPS) ? gPos[tid] : 0.f;
    __syncthreads();
    for (int off = 1; off < 128; off <<= 1) {
        float v = 0.f;
        if (tid < 128 && tid >= off) v = scanbuf[tid - off];
        __syncthreads();
        if (tid < 128) scanbuf[tid] += v;
        __syncthreads();
    }
    const float invsp = 1.0f / scanbuf[NSTEPS - 1];
    for (int i = tid; i < NREPC2 * NSTEPS; i += 256) {
        int r = i / NSTEPS, b = i - r * NSTEPS;
        float c0 = scanbuf[b] * invsp;
        float c1 = ((b < NSTEPS - 1) ? scanbuf[b + 1] : scanbuf[NSTEPS - 1]) * invsp;
        float2 cd; cd.x = c0; cd.y = c1 - c0;
        cdf2[r * 101 + b] = cd;
    }

    // unit decode
    int ti0, tj0, ti1 = 0, nu = 1;
    {
        int t = bid;
        if (t < NOFF) {
            int ti = 0, rem = t;
            while (rem >= GRID_T - 1 - ti) { rem -= GRID_T - 1 - ti; ++ti; }
            ti0 = ti; tj0 = ti + 1 + rem;
        } else {
            int d = (t - NOFF) * 2;
            ti0 = tj0 = d; ti1 = d + 1; nu = 2;
        }
    }

    const int wr = wid >> 1, wc = wid & 1;
    const int lr = lane & 15;
    const int kg = lane >> 4;
    const float2* crep2 = &cdf2[(lane & 7) * 101];
    const int li_base = wr * 64 + (kg << 2);
    const int lj_base = wc * 64 + lr;

    float lacc = 0.f, lcnt = 0.f;
    const int rloc = lane >> 4;
    const int pch = lane & 15;

    for (int u = 0; u < nu; ++u) {
        const int ti = u ? ti1 : ti0;
        const int tj = u ? ti1 : tj0;
        const bool diag = (ti == tj);

        __syncthreads();
        if (tid < PTILE) clsA[tid] = cls[ti * PTILE + tid];
        else             clsB[tid - PTILE] = cls[tj * PTILE + (tid - PTILE)];

        {
            const ushort* Ag = nemb + (size_t)(ti * PTILE) * DD;
            const ushort* Bg = nemb + (size_t)(tj * PTILE) * DD;
            #pragma unroll
            for (int t = 0; t < 8; ++t) {
                int row = wid * 32 + t * 4 + rloc;
                int lch = pch ^ (row & 7);
                const ushort* ga = Ag + (size_t)row * DD + lch * 8;
                ushort* la = &As[(wid * 32 + t * 4) * 128];
                __builtin_amdgcn_global_load_lds(
                    (const __attribute__((address_space(1))) void*)ga,
                    (__attribute__((address_space(3))) void*)la, 16, 0, 0);
            }
            if (!diag) {
                #pragma unroll
                for (int t = 0; t < 8; ++t) {
                    int row = wid * 32 + t * 4 + rloc;
                    int lch = pch ^ (row & 7);
                    const ushort* gb = Bg + (size_t)row * DD + lch * 8;
                    ushort* lb = &Bs[(wid * 32 + t * 4) * 128];
                    __builtin_amdgcn_global_load_lds(
                        (const __attribute__((address_space(1))) void*)gb,
                        (__attribute__((address_space(3))) void*)lb, 16, 0, 0);
                }
            }
        }
        __syncthreads();

        const ushort* Bsel = diag ? As : Bs;
        const int* clsBsel = diag ? clsA : clsB;

        f32x4 zero4 = {0.f, 0.f, 0.f, 0.f};
        f32x4 acc[4][4];
        #pragma unroll
        for (int a = 0; a < 4; ++a)
            #pragma unroll
            for (int b = 0; b < 4; ++b) acc[a][b] = zero4;

        #pragma unroll
        for (int ks = 0; ks < 4; ++ks) {
            bf16x8 af[4], bfr[4];
            #pragma unroll
            for (int f = 0; f < 4; ++f) {
                int arow = wr * 64 + f * 16 + lr;
                int pca = ((ks << 2) | kg) ^ (arow & 7);
                af[f] = *(const bf16x8*)(&As[arow * 128 + pca * 8]);
                int brow = wc * 64 + f * 16 + lr;
                int pcb = ((ks << 2) | kg) ^ (brow & 7);
                bfr[f] = *(const bf16x8*)(&Bsel[brow * 128 + pcb * 8]);
            }
            #pragma unroll
            for (int fa = 0; fa < 4; ++fa)
                #pragma unroll
                for (int fb = 0; fb < 4; ++fb)
                    acc[fa][fb] = __builtin_amdgcn_mfma_f32_16x16x32_bf16(af[fa], bfr[fb], acc[fa][fb], 0, 0, 0);
        }

        int ca[16];
        #pragma unroll
        for (int fa = 0; fa < 4; ++fa)
            #pragma unroll
            for (int j = 0; j < 4; ++j) ca[fa * 4 + j] = clsA[li_base + fa * 16 + j];

        const bool offdiag = !diag;
        #pragma unroll
        for (int fb = 0; fb < 4; ++fb) {
            const int lj = lj_base + fb * 16;
            const int cb = clsBsel[lj];
            #pragma unroll
            for (int fa = 0; fa < 4; ++fa) {
                const int li0 = li_base + fa * 16;
                f32x4 v = acc[fa][fb];
                #pragma unroll
                for (int j = 0; j < 4; ++j) {
                    const int li = li0 + j;
                    const bool mneg = (offdiag || (li < lj)) && (ca[fa * 4 + j] != cb);
                    float s = v[j];
                    s = fminf(fmaxf(s, -CLIPV), CLIPV);
                    float uu = (s + CLIPV) * INVSTEP;
                    int jb = (int)uu;
                    if (jb > 98) jb = 98;
                    float w_hi = uu - (float)jb;          // == (s - t_j)*INVSTEP
                    float2 cd = crep2[jb];                // one ds_read_b64
                    float mm = mneg ? 1.0f : 0.0f;
                    lacc = fmaf(mm, fmaf(w_hi, cd.y, cd.x), lacc);
                    lcnt += mm;
                }
            }
        }
    }

    // reduce + final
    #pragma unroll
    for (int off = 32; off > 0; off >>= 1) {
        lacc += __shfl_xor(lacc, off);
        lcnt += __shfl_xor(lcnt, off);
    }
    if (lane == 0) { red[wid] = lacc; red[4 + wid] = lcnt; }
    __syncthreads();
    if (tid == 0) {
        float L = red[0] + red[1] + red[2] + red[3];
        float C = red[4] + red[5] + red[6] + red[7];
        faddf(&gLoss[bid & 31], L);
        faddf(&gCnt[bid & 31], C);
        __threadfence();
        unsigned int tk = atomicAdd(gDone, 1u);
        if (tk == NBLK2 - 1) {
            __threadfence();
            float ls = 0.f, cs = 0.f;
            for (int i = 0; i < 32; ++i) {
                ls += __hip_atomic_load(&gLoss[i], __ATOMIC_RELAXED, __HIP_MEMORY_SCOPE_AGENT);
                cs += __hip_atomic_load(&gCnt[i], __ATOMIC_RELAXED, __HIP_MEMORY_SCOPE_AGENT);
            }
            out[0] = ls / cs;            // cdf already contains 1/sp
        }
    }
}

extern "C" void kernel_launch(void* const* d_in, const int* in_sizes, int n_in,
                              void* d_out, int out_size, void* d_ws, size_t ws_size,
                              hipStream_t stream) {
    const float* emb = (const float*)d_in[0];
    const int* classes = (const int*)d_in[1];
    float* out = (float*)d_out;

    ushort* nemb = (ushort*)d_ws;                                   // 1 MB
    float* ctl = (float*)((char*)d_ws + (size_t)BN * DD * sizeof(ushort));
    float* gPos = ctl;                                  // 100
    float* gLoss = gPos + NSTEPS;                       // 32
    float* gCnt = gLoss + 32;                           // 32
    unsigned int* gDone = (unsigned int*)(gCnt + 32);   // 1
    unsigned int* gBar1 = gDone + 1;                    // 1
    unsigned int* gBar2 = gBar1 + 1;                    // 1

    hipMemsetAsync(ctl, 0, 167 * sizeof(float), stream);
    hl_fused<<<NBLK2, 256, 0, stream>>>(emb, classes, nemb, gPos, gLoss, gCnt,
                                        gDone, gBar1, gBar2, out);
}

// Round 28
// 51.641 us; speedup vs baseline: 4.4910x; 2.3585x over previous
//
#include <hip/hip_runtime.h>
#include <hip/hip_bf16.h>
#include <cstddef>

#define BN 4096
#define DD 128
#define NSTEPS 100
#define PTILE 128
#define PLSTR 136   // poscls LDS row stride (padded)
#define GRID_T 32
#define NOFF 496    // strictly-upper tile pairs (ti<tj)
#define NBLK2 512   // 496 off-diag + 16 blocks x 2 diagonal tiles
#define NREPH 16    // poscls hist replicas
#define NREPC2 8    // cdf float2 replicas (stride 101)

typedef __attribute__((ext_vector_type(8))) short bf16x8;
typedef __attribute__((ext_vector_type(4))) float f32x4;

__device__ __forceinline__ void faddf(float* p, float v) { unsafeAtomicAdd(p, v); }

// ws ctl: gPos[100] gLoss[32] gCnt[32] gDone gDoneP  (166 words) | gCdf[100]
#define ZERON 166

// ---------------- normalize + convert to bf16 + zero control block ----------------
__global__ __launch_bounds__(256) void hl_normalize(const float* __restrict__ emb,
                                                    ushort* __restrict__ out,
                                                    float* __restrict__ zero_blk) {
    if (blockIdx.x == 0 && threadIdx.x < ZERON) zero_blk[threadIdx.x] = 0.f;
    int w = threadIdx.x >> 6;
    int lane = threadIdx.x & 63;
    int row = (blockIdx.x << 2) + w;
    const float2 v = *(const float2*)(emb + (size_t)row * DD + 2 * lane);
    float ss = v.x * v.x + v.y * v.y;
    #pragma unroll
    for (int off = 32; off > 0; off >>= 1) ss += __shfl_xor(ss, off);
    float inv = 1.0f / sqrtf(ss);
    __hip_bfloat16 b0 = __float2bfloat16(v.x * inv);
    __hip_bfloat16 b1 = __float2bfloat16(v.y * inv);
    ushort2 pk;
    pk.x = *(ushort*)&b0;
    pk.y = *(ushort*)&b1;
    *(ushort2*)(out + (size_t)row * DD + 2 * lane) = pk;
}

// ---------------- POS histogram: per-class MFMA gram; last block builds cdf ----------
__global__ __launch_bounds__(256) void hl_poscls(const ushort* __restrict__ nemb,
                                                 const int* __restrict__ cls,
                                                 float* __restrict__ gPos,
                                                 unsigned int* __restrict__ gDoneP,
                                                 float* __restrict__ gCdf) {
    const int c = blockIdx.x;
    __shared__ int idx[256];
    __shared__ int scan[256];
    __shared__ ushort As[64 * PLSTR];
    __shared__ ushort Bs[64 * PLSTR];
    __shared__ float hpos[NREPH * 101];
    __shared__ int mTot;
    __shared__ int lastFlag;
    const int tid = threadIdx.x;

    for (int i = tid; i < NREPH * 101; i += 256) hpos[i] = 0.f;

    const int base = tid * 16;
    int myCnt = 0;
    #pragma unroll
    for (int k = 0; k < 16; ++k) myCnt += (cls[base + k] == c);
    scan[tid] = myCnt;
    __syncthreads();
    for (int s = 1; s < 256; s <<= 1) {
        int v = (tid >= s) ? scan[tid - s] : 0;
        __syncthreads();
        scan[tid] += v;
        __syncthreads();
    }
    int w = scan[tid] - myCnt;
    if (tid == 255) mTot = scan[255] > 256 ? 256 : scan[255];
    #pragma unroll
    for (int k = 0; k < 16; ++k) {
        if (cls[base + k] == c && w < 256) { idx[w] = base + k; ++w; }
    }
    __syncthreads();
    const int m = mTot;
    const int nt = (m + 63) >> 6;

    constexpr float INVSTEP = 49.5f;
    constexpr float CLIPV = 1.0f - 1e-6f;

    const int lane = tid & 63;
    const int wv = tid >> 6;
    const int lr = lane & 15;
    const int kg = lane >> 4;
    const int rep = (lane & 15) * 101;

    for (int si = 0; si < nt; ++si) {
        for (int sj = si; sj < nt; ++sj) {
            __syncthreads();
            #pragma unroll
            for (int it = 0; it < 4; ++it) {
                int q = it * 256 + tid;
                int row = q >> 4;
                int ch = q & 15;
                int ga = si * 64 + row;
                int gb = sj * 64 + row;
                int ra = idx[ga < m ? ga : 0];
                int rb = idx[gb < m ? gb : 0];
                *(float4*)(&As[row * PLSTR + ch * 8]) =
                    *(const float4*)(nemb + (size_t)ra * DD + ch * 8);
                *(float4*)(&Bs[row * PLSTR + ch * 8]) =
                    *(const float4*)(nemb + (size_t)rb * DD + ch * 8);
            }
            __syncthreads();

            f32x4 zero4 = {0.f, 0.f, 0.f, 0.f};
            f32x4 pacc[4] = {zero4, zero4, zero4, zero4};
            #pragma unroll
            for (int ks = 0; ks < 4; ++ks) {
                bf16x8 af = *(const bf16x8*)(&As[(wv * 16 + lr) * PLSTR + ks * 32 + kg * 8]);
                #pragma unroll
                for (int fb = 0; fb < 4; ++fb) {
                    bf16x8 bf = *(const bf16x8*)(&Bs[(fb * 16 + lr) * PLSTR + ks * 32 + kg * 8]);
                    pacc[fb] = __builtin_amdgcn_mfma_f32_16x16x32_bf16(af, bf, pacc[fb], 0, 0, 0);
                }
            }

            #pragma unroll
            for (int fb = 0; fb < 4; ++fb) {
                const int gb = sj * 64 + fb * 16 + lr;
                #pragma unroll
                for (int j = 0; j < 4; ++j) {
                    const int ga = si * 64 + wv * 16 + kg * 4 + j;
                    if (ga < gb && gb < m) {
                        float s = pacc[fb][j];
                        s = fminf(fmaxf(s, -CLIPV), CLIPV);
                        float u = (s + CLIPV) * INVSTEP;
                        int jb = (int)u;
                        if (jb > 98) jb = 98;
                        float w_hi = u - (float)jb;
                        float w_lo = 1.0f - w_hi;
                        faddf(&hpos[rep + jb], w_lo);
                        faddf(&hpos[rep + jb + 1], w_hi);
                    }
                }
            }
        }
    }
    __syncthreads();
    if (tid < NSTEPS) {
        float v = 0.f;
        #pragma unroll
        for (int r = 0; r < NREPH; ++r) v += hpos[r * 101 + tid];
        if (v != 0.f) faddf(&gPos[tid], v);
    }
    __threadfence();
    if (tid == 0) {
        unsigned int tk = atomicAdd(gDoneP, 1u);
        lastFlag = (tk == NSTEPS - 1);
    }
    __syncthreads();
    if (lastFlag) {
        float v = (tid < NSTEPS)
            ? __hip_atomic_load(&gPos[tid], __ATOMIC_RELAXED, __HIP_MEMORY_SCOPE_AGENT) : 0.f;
        if (tid < 128) hpos[tid] = v;
        __syncthreads();
        for (int off = 1; off < 128; off <<= 1) {
            float x = 0.f;
            if (tid < 128 && tid >= off) x = hpos[tid - off];
            __syncthreads();
            if (tid < 128) hpos[tid] += x;
            __syncthreads();
        }
        const float invsp = 1.0f / hpos[NSTEPS - 1];
        if (tid < NSTEPS) gCdf[tid] = hpos[tid] * invsp;
    }
}

// ---------------- NEG pass: compact-code MFMA GEMM + LDS-spilled epilogue ----------
// r28: epilogue rewritten as acc->LDS spill + runtime 64-iter loop. Code size
// ~10x smaller (I-cache thrash hypothesis for the 29us-vs-6us-model gap).
__global__ __launch_bounds__(256, 2) void hl_neg(const ushort* __restrict__ nemb,
                                                 const int* __restrict__ cls,
                                                 const float* __restrict__ gCdf,
                                                 float* __restrict__ gLoss,
                                                 float* __restrict__ gCnt,
                                                 unsigned int* __restrict__ gDone,
                                                 float* __restrict__ out) {
    __shared__ __align__(16) char arena[65536];   // A,B tiles; accL after MFMA
    ushort* As = (ushort*)arena;                  // 32768 B
    ushort* Bs = (ushort*)(arena + 32768);        // 32768 B
    float* accL = (float*)arena;                  // 64 KB: [p][256] columns
    __shared__ float2 cdf2[NREPC2 * 101];         // 6464 B
    __shared__ float red[8];
    __shared__ int clsA[PTILE], clsB[PTILE];

    const int tid = threadIdx.x;
    const int lane = tid & 63;
    const int wid = tid >> 6;
    const int wr = wid >> 1, wc = wid & 1;
    const int lr = lane & 15;
    const int kg = lane >> 4;

    int ti0, tj0, ti1 = 0, nu = 1;
    {
        int t = blockIdx.x;
        if (t < NOFF) {
            int ti = 0, rem = t;
            while (rem >= GRID_T - 1 - ti) { rem -= GRID_T - 1 - ti; ++ti; }
            ti0 = ti; tj0 = ti + 1 + rem;
        } else {
            int d = (t - NOFF) * 2;
            ti0 = tj0 = d; ti1 = d + 1; nu = 2;
        }
    }

    // cdf float2{c0, c1-c0} replicas -> one ds_read_b64 per pair
    for (int i = tid; i < NREPC2 * NSTEPS; i += 256) {
        int r = i / NSTEPS, b = i - r * NSTEPS;
        float c0 = gCdf[b];
        float c1 = gCdf[(b < NSTEPS - 1) ? b + 1 : NSTEPS - 1];
        float2 cd; cd.x = c0; cd.y = c1 - c0;
        cdf2[r * 101 + b] = cd;
    }

    constexpr float INVSTEP = 49.5f;
    constexpr float CLIPV = 1.0f - 1e-6f;
    const float2* crep2 = &cdf2[(lane & 7) * 101];
    const int li_base = wr * 64 + (kg << 2);
    const int lj_base = wc * 64 + lr;

    float lacc = 0.f, lcnt = 0.f;
    const int rloc = lane >> 4;
    const int pch = lane & 15;

    for (int u = 0; u < nu; ++u) {
        const int ti = u ? ti1 : ti0;
        const int tj = u ? ti1 : tj0;
        const bool diag = (ti == tj);

        __syncthreads();                 // prior unit's accL reads complete
        if (tid < PTILE) clsA[tid] = cls[ti * PTILE + tid];
        else             clsB[tid - PTILE] = cls[tj * PTILE + (tid - PTILE)];

        // stage via global_load_lds(16B), XOR-swizzled global source (rule 21)
        {
            const ushort* Ag = nemb + (size_t)(ti * PTILE) * DD;
            const ushort* Bg = nemb + (size_t)(tj * PTILE) * DD;
            #pragma unroll
            for (int t = 0; t < 8; ++t) {
                int row = wid * 32 + t * 4 + rloc;
                int lch = pch ^ (row & 7);
                const ushort* ga = Ag + (size_t)row * DD + lch * 8;
                ushort* la = &As[(wid * 32 + t * 4) * 128];
                __builtin_amdgcn_global_load_lds(
                    (const __attribute__((address_space(1))) void*)ga,
                    (__attribute__((address_space(3))) void*)la, 16, 0, 0);
            }
            if (!diag) {
                #pragma unroll
                for (int t = 0; t < 8; ++t) {
                    int row = wid * 32 + t * 4 + rloc;
                    int lch = pch ^ (row & 7);
                    const ushort* gb = Bg + (size_t)row * DD + lch * 8;
                    ushort* lb = &Bs[(wid * 32 + t * 4) * 128];
                    __builtin_amdgcn_global_load_lds(
                        (const __attribute__((address_space(1))) void*)gb,
                        (__attribute__((address_space(3))) void*)lb, 16, 0, 0);
                }
            }
        }
        __syncthreads();

        const ushort* Bsel = diag ? As : Bs;
        const int* clsBsel = diag ? clsA : clsB;

        f32x4 zero4 = {0.f, 0.f, 0.f, 0.f};
        f32x4 acc[4][4];
        #pragma unroll
        for (int a = 0; a < 4; ++a)
            #pragma unroll
            for (int b = 0; b < 4; ++b) acc[a][b] = zero4;

        #pragma unroll
        for (int ks = 0; ks < 4; ++ks) {
            bf16x8 af[4], bfr[4];
            #pragma unroll
            for (int f = 0; f < 4; ++f) {
                int arow = wr * 64 + f * 16 + lr;
                int pca = ((ks << 2) | kg) ^ (arow & 7);
                af[f] = *(const bf16x8*)(&As[arow * 128 + pca * 8]);
                int brow = wc * 64 + f * 16 + lr;
                int pcb = ((ks << 2) | kg) ^ (brow & 7);
                bfr[f] = *(const bf16x8*)(&Bsel[brow * 128 + pcb * 8]);
            }
            #pragma unroll
            for (int fa = 0; fa < 4; ++fa)
                #pragma unroll
                for (int fb = 0; fb < 4; ++fb)
                    acc[fa][fb] = __builtin_amdgcn_mfma_f32_16x16x32_bf16(af[fa], bfr[fb], acc[fa][fb], 0, 0, 0);
        }

        __syncthreads();   // all MFMA LDS reads done; tiles now dead

        // spill acc -> accL[p*256 + tid], p = fb*16 + fa*4 + j (conflict-free)
        #pragma unroll
        for (int fb = 0; fb < 4; ++fb)
            #pragma unroll
            for (int fa = 0; fa < 4; ++fa)
                #pragma unroll
                for (int j = 0; j < 4; ++j)
                    accL[(fb * 16 + fa * 4 + j) * 256 + tid] = acc[fa][fb][j];
        __syncthreads();

        const bool offdiag = !diag;
        // compact runtime epilogue loop: p uniform -> fb/fa/j scalar
        #pragma unroll 1
        for (int p = 0; p < 64; ++p) {
            const int fb = p >> 4, fa = (p >> 2) & 3, j = p & 3;
            const int li = li_base + fa * 16 + j;
            const int lj = lj_base + fb * 16;
            float s = accL[p * 256 + tid];
            int ca = clsA[li];
            int cb = clsBsel[lj];
            const bool mneg = (offdiag || (li < lj)) && (ca != cb);
            s = fminf(fmaxf(s, -CLIPV), CLIPV);
            float uu = (s + CLIPV) * INVSTEP;
            int jb = (int)uu;
            if (jb > 98) jb = 98;
            float w_hi = uu - (float)jb;
            float2 cd = crep2[jb];
            float mm = mneg ? 1.0f : 0.0f;
            lacc = fmaf(mm, fmaf(w_hi, cd.y, cd.x), lacc);
            lcnt += mm;
        }
    }

    // reduce: wave shuffle -> 4 partials -> 2 atomics into 32 slots
    #pragma unroll
    for (int off = 32; off > 0; off >>= 1) {
        lacc += __shfl_xor(lacc, off);
        lcnt += __shfl_xor(lcnt, off);
    }
    if (lane == 0) { red[wid] = lacc; red[4 + wid] = lcnt; }
    __syncthreads();
    if (tid == 0) {
        float L = red[0] + red[1] + red[2] + red[3];
        float C = red[4] + red[5] + red[6] + red[7];
        faddf(&gLoss[blockIdx.x & 31], L);
        faddf(&gCnt[blockIdx.x & 31], C);
        __threadfence();
        unsigned int tk = atomicAdd(gDone, 1u);
        if (tk == NBLK2 - 1) {
            __threadfence();
            float ls = 0.f, cs = 0.f;
            for (int i = 0; i < 32; ++i) {
                ls += __hip_atomic_load(&gLoss[i], __ATOMIC_RELAXED, __HIP_MEMORY_SCOPE_AGENT);
                cs += __hip_atomic_load(&gCnt[i], __ATOMIC_RELAXED, __HIP_MEMORY_SCOPE_AGENT);
            }
            out[0] = ls / cs;            // cdf already contains 1/sp
        }
    }
}

extern "C" void kernel_launch(void* const* d_in, const int* in_sizes, int n_in,
                              void* d_out, int out_size, void* d_ws, size_t ws_size,
                              hipStream_t stream) {
    const float* emb = (const float*)d_in[0];
    const int* classes = (const int*)d_in[1];
    float* out = (float*)d_out;

    ushort* nemb = (ushort*)d_ws;                                   // 1 MB
    float* ctl = (float*)((char*)d_ws + (size_t)BN * DD * sizeof(ushort));
    float* gPos = ctl;                                // 100
    float* gLoss = gPos + NSTEPS;                     // 32
    float* gCnt = gLoss + 32;                         // 32
    unsigned int* gDone = (unsigned int*)(gCnt + 32); // 1
    unsigned int* gDoneP = gDone + 1;                 // 1
    float* gCdf = (float*)(gDoneP + 1);               // 100 (fully written)

    hl_normalize<<<BN / 4, 256, 0, stream>>>(emb, nemb, ctl);
    hl_poscls<<<NSTEPS, 256, 0, stream>>>(nemb, classes, gPos, gDoneP, gCdf);
    hl_neg<<<NBLK2, 256, 0, stream>>>(nemb, classes, gCdf, gLoss, gCnt, gDone, out);
}

// Round 29
// 42.002 us; speedup vs baseline: 5.5216x; 1.2295x over previous
//
#include <hip/hip_runtime.h>
#include <hip/hip_bf16.h>
#include <cstddef>

#define BN 4096
#define DD 128
#define NSTEPS 100
#define PTILE 128
#define PLSTR 136   // poscls LDS row stride (padded)
#define GRID_T 32
#define NOFF 496    // strictly-upper tile pairs (ti<tj)
#define NUNITS 528  // 496 off-diag + 32 diag
#define NBLK 264    // 2 units per block
#define NREPH 16
#define NREPC2 8    // cdf float2 replicas (stride 101)

typedef __attribute__((ext_vector_type(8))) short bf16x8;
typedef __attribute__((ext_vector_type(4))) float f32x4;

__device__ __forceinline__ void faddf(float* p, float v) { unsafeAtomicAdd(p, v); }

// ws ctl: gPos[100] gLoss[32] gCnt[32] gDone gDoneP  (166 words) | gCdf[100]
#define ZERON 166

// ---------------- normalize + convert to bf16 + zero control block ----------------
__global__ __launch_bounds__(256) void hl_normalize(const float* __restrict__ emb,
                                                    ushort* __restrict__ out,
                                                    float* __restrict__ zero_blk) {
    if (blockIdx.x == 0 && threadIdx.x < ZERON) zero_blk[threadIdx.x] = 0.f;
    int w = threadIdx.x >> 6;
    int lane = threadIdx.x & 63;
    int row = (blockIdx.x << 2) + w;
    const float2 v = *(const float2*)(emb + (size_t)row * DD + 2 * lane);
    float ss = v.x * v.x + v.y * v.y;
    #pragma unroll
    for (int off = 32; off > 0; off >>= 1) ss += __shfl_xor(ss, off);
    float inv = 1.0f / sqrtf(ss);
    __hip_bfloat16 b0 = __float2bfloat16(v.x * inv);
    __hip_bfloat16 b1 = __float2bfloat16(v.y * inv);
    ushort2 pk;
    pk.x = *(ushort*)&b0;
    pk.y = *(ushort*)&b1;
    *(ushort2*)(out + (size_t)row * DD + 2 * lane) = pk;
}

// ---------------- POS histogram: per-class MFMA gram; last block builds cdf ----------
__global__ __launch_bounds__(256) void hl_poscls(const ushort* __restrict__ nemb,
                                                 const int* __restrict__ cls,
                                                 float* __restrict__ gPos,
                                                 unsigned int* __restrict__ gDoneP,
                                                 float* __restrict__ gCdf) {
    const int c = blockIdx.x;
    __shared__ int idx[256];
    __shared__ int scan[256];
    __shared__ ushort As[64 * PLSTR];
    __shared__ ushort Bs[64 * PLSTR];
    __shared__ float hpos[NREPH * 101];
    __shared__ int mTot;
    __shared__ int lastFlag;
    const int tid = threadIdx.x;

    for (int i = tid; i < NREPH * 101; i += 256) hpos[i] = 0.f;

    const int base = tid * 16;
    int myCnt = 0;
    #pragma unroll
    for (int k = 0; k < 16; ++k) myCnt += (cls[base + k] == c);
    scan[tid] = myCnt;
    __syncthreads();
    for (int s = 1; s < 256; s <<= 1) {
        int v = (tid >= s) ? scan[tid - s] : 0;
        __syncthreads();
        scan[tid] += v;
        __syncthreads();
    }
    int w = scan[tid] - myCnt;
    if (tid == 255) mTot = scan[255] > 256 ? 256 : scan[255];
    #pragma unroll
    for (int k = 0; k < 16; ++k) {
        if (cls[base + k] == c && w < 256) { idx[w] = base + k; ++w; }
    }
    __syncthreads();
    const int m = mTot;
    const int nt = (m + 63) >> 6;

    constexpr float INVSTEP = 49.5f;
    constexpr float CLIPV = 1.0f - 1e-6f;

    const int lane = tid & 63;
    const int wv = tid >> 6;
    const int lr = lane & 15;
    const int kg = lane >> 4;
    const int rep = (lane & 15) * 101;

    for (int si = 0; si < nt; ++si) {
        for (int sj = si; sj < nt; ++sj) {
            __syncthreads();
            #pragma unroll
            for (int it = 0; it < 4; ++it) {
                int q = it * 256 + tid;
                int row = q >> 4;
                int ch = q & 15;
                int ga = si * 64 + row;
                int gb = sj * 64 + row;
                int ra = idx[ga < m ? ga : 0];
                int rb = idx[gb < m ? gb : 0];
                *(float4*)(&As[row * PLSTR + ch * 8]) =
                    *(const float4*)(nemb + (size_t)ra * DD + ch * 8);
                *(float4*)(&Bs[row * PLSTR + ch * 8]) =
                    *(const float4*)(nemb + (size_t)rb * DD + ch * 8);
            }
            __syncthreads();

            f32x4 zero4 = {0.f, 0.f, 0.f, 0.f};
            f32x4 pacc[4] = {zero4, zero4, zero4, zero4};
            #pragma unroll
            for (int ks = 0; ks < 4; ++ks) {
                bf16x8 af = *(const bf16x8*)(&As[(wv * 16 + lr) * PLSTR + ks * 32 + kg * 8]);
                #pragma unroll
                for (int fb = 0; fb < 4; ++fb) {
                    bf16x8 bf = *(const bf16x8*)(&Bs[(fb * 16 + lr) * PLSTR + ks * 32 + kg * 8]);
                    pacc[fb] = __builtin_amdgcn_mfma_f32_16x16x32_bf16(af, bf, pacc[fb], 0, 0, 0);
                }
            }

            #pragma unroll
            for (int fb = 0; fb < 4; ++fb) {
                const int gb = sj * 64 + fb * 16 + lr;
                #pragma unroll
                for (int j = 0; j < 4; ++j) {
                    const int ga = si * 64 + wv * 16 + kg * 4 + j;
                    if (ga < gb && gb < m) {
                        float s = pacc[fb][j];
                        s = fminf(fmaxf(s, -CLIPV), CLIPV);
                        float u = (s + CLIPV) * INVSTEP;
                        int jb = (int)u;
                        if (jb > 98) jb = 98;
                        float w_hi = u - (float)jb;
                        float w_lo = 1.0f - w_hi;
                        faddf(&hpos[rep + jb], w_lo);
                        faddf(&hpos[rep + jb + 1], w_hi);
                    }
                }
            }
        }
    }
    __syncthreads();
    if (tid < NSTEPS) {
        float v = 0.f;
        #pragma unroll
        for (int r = 0; r < NREPH; ++r) v += hpos[r * 101 + tid];
        if (v != 0.f) faddf(&gPos[tid], v);
    }
    __threadfence();
    if (tid == 0) {
        unsigned int tk = atomicAdd(gDoneP, 1u);
        lastFlag = (tk == NSTEPS - 1);
    }
    __syncthreads();
    if (lastFlag) {
        float v = (tid < NSTEPS)
            ? __hip_atomic_load(&gPos[tid], __ATOMIC_RELAXED, __HIP_MEMORY_SCOPE_AGENT) : 0.f;
        if (tid < 128) hpos[tid] = v;
        __syncthreads();
        for (int off = 1; off < 128; off <<= 1) {
            float x = 0.f;
            if (tid < 128 && tid >= off) x = hpos[tid - off];
            __syncthreads();
            if (tid < 128) hpos[tid] += x;
            __syncthreads();
        }
        const float invsp = 1.0f / hpos[NSTEPS - 1];
        if (tid < NSTEPS) gCdf[tid] = hpos[tid] * invsp;
    }
}

// ---------------- NEG pass: 2-unit software-pipelined MFMA + cdf gather ----------
// r29: 264 blocks x 2 units. Unit u+1's global_load_lds is issued right after
// unit u's post-MFMA barrier; the register epilogue(u) (touches only acc/cdf2/
// cls) hides the staging flight. One exposed staging latency per BLOCK instead
// of per unit.
__global__ __launch_bounds__(256, 2) void hl_neg(const ushort* __restrict__ nemb,
                                                 const int* __restrict__ cls,
                                                 const float* __restrict__ gCdf,
                                                 float* __restrict__ gLoss,
                                                 float* __restrict__ gCnt,
                                                 unsigned int* __restrict__ gDone,
                                                 float* __restrict__ out) {
    __shared__ ushort As[PTILE * 128];        // 32768 B (gload_lds dest)
    __shared__ ushort Bs[PTILE * 128];        // 32768 B
    __shared__ float2 cdf2[NREPC2 * 101];     // 6464 B
    __shared__ float red[8];
    __shared__ int clsAb[2][PTILE], clsBb[2][PTILE];

    const int tid = threadIdx.x;
    const int lane = tid & 63;
    const int wid = tid >> 6;
    const int wr = wid >> 1, wc = wid & 1;
    const int lr = lane & 15;
    const int kg = lane >> 4;

    // decode both units of this block
    int tiU[2], tjU[2];
    #pragma unroll
    for (int u = 0; u < 2; ++u) {
        int id = blockIdx.x * 2 + u;
        if (id < NOFF) {
            int ti = 0, rem = id;
            while (rem >= GRID_T - 1 - ti) { rem -= GRID_T - 1 - ti; ++ti; }
            tiU[u] = ti; tjU[u] = ti + 1 + rem;
        } else {
            tiU[u] = tjU[u] = id - NOFF;
        }
    }

    // cdf float2{c0, c1-c0} replicas -> one ds_read_b64 per pair
    for (int i = tid; i < NREPC2 * NSTEPS; i += 256) {
        int r = i / NSTEPS, b = i - r * NSTEPS;
        float c0 = gCdf[b];
        float c1 = gCdf[(b < NSTEPS - 1) ? b + 1 : NSTEPS - 1];
        float2 cd; cd.x = c0; cd.y = c1 - c0;
        cdf2[r * 101 + b] = cd;
    }

    constexpr float INVSTEP = 49.5f;
    constexpr float CLIPV = 1.0f - 1e-6f;
    const float2* crep2 = &cdf2[(lane & 7) * 101];
    const int li_base = wr * 64 + (kg << 2);
    const int lj_base = wc * 64 + lr;

    float lacc = 0.f, lcnt = 0.f;
    const int rloc = lane >> 4;
    const int pch = lane & 15;

    // staging helper expressed inline: unit u -> As (+Bs if offdiag), cls buf u&1
    #define STAGE_UNIT(U)                                                            \
    {                                                                                \
        const int ti_ = tiU[U], tj_ = tjU[U];                                        \
        const bool dg_ = (ti_ == tj_);                                               \
        if (tid < PTILE) clsAb[(U) & 1][tid] = cls[ti_ * PTILE + tid];               \
        else             clsBb[(U) & 1][tid - PTILE] = cls[tj_ * PTILE + (tid - PTILE)]; \
        const ushort* Ag_ = nemb + (size_t)(ti_ * PTILE) * DD;                       \
        const ushort* Bg_ = nemb + (size_t)(tj_ * PTILE) * DD;                       \
        _Pragma("unroll")                                                            \
        for (int t = 0; t < 8; ++t) {                                                \
            int row = wid * 32 + t * 4 + rloc;                                       \
            int lch = pch ^ (row & 7);                                               \
            const ushort* ga = Ag_ + (size_t)row * DD + lch * 8;                     \
            ushort* la = &As[(wid * 32 + t * 4) * 128];                              \
            __builtin_amdgcn_global_load_lds(                                        \
                (const __attribute__((address_space(1))) void*)ga,                   \
                (__attribute__((address_space(3))) void*)la, 16, 0, 0);              \
        }                                                                            \
        if (!dg_) {                                                                  \
            _Pragma("unroll")                                                        \
            for (int t = 0; t < 8; ++t) {                                            \
                int row = wid * 32 + t * 4 + rloc;                                   \
                int lch = pch ^ (row & 7);                                           \
                const ushort* gb = Bg_ + (size_t)row * DD + lch * 8;                 \
                ushort* lb = &Bs[(wid * 32 + t * 4) * 128];                          \
                __builtin_amdgcn_global_load_lds(                                    \
                    (const __attribute__((address_space(1))) void*)gb,               \
                    (__attribute__((address_space(3))) void*)lb, 16, 0, 0);          \
            }                                                                        \
        }                                                                            \
    }

    STAGE_UNIT(0);   // prologue: stage unit 0

    #pragma unroll
    for (int u = 0; u < 2; ++u) {
        const bool diag = (tiU[u] == tjU[u]);

        __syncthreads();   // compiler drains vmcnt before barrier -> tiles(u)+cls(u) ready

        const ushort* Bsel = diag ? As : Bs;

        f32x4 zero4 = {0.f, 0.f, 0.f, 0.f};
        f32x4 acc[4][4];
        #pragma unroll
        for (int a = 0; a < 4; ++a)
            #pragma unroll
            for (int b = 0; b < 4; ++b) acc[a][b] = zero4;

        #pragma unroll
        for (int ks = 0; ks < 4; ++ks) {
            bf16x8 af[4], bfr[4];
            #pragma unroll
            for (int f = 0; f < 4; ++f) {
                int arow = wr * 64 + f * 16 + lr;
                int pca = ((ks << 2) | kg) ^ (arow & 7);
                af[f] = *(const bf16x8*)(&As[arow * 128 + pca * 8]);
                int brow = wc * 64 + f * 16 + lr;
                int pcb = ((ks << 2) | kg) ^ (brow & 7);
                bfr[f] = *(const bf16x8*)(&Bsel[brow * 128 + pcb * 8]);
            }
            #pragma unroll
            for (int fa = 0; fa < 4; ++fa)
                #pragma unroll
                for (int fb = 0; fb < 4; ++fb)
                    acc[fa][fb] = __builtin_amdgcn_mfma_f32_16x16x32_bf16(af[fa], bfr[fb], acc[fa][fb], 0, 0, 0);
        }

        __syncthreads();   // all waves done reading tiles(u): safe to overwrite

        if (u == 0) STAGE_UNIT(1);   // prefetch unit 1; flight hides under epilogue(0)

        // register epilogue(u): touches only acc, cdf2, cls buf u&1
        const int* clsA_ = clsAb[u & 1];
        const int* clsB_ = diag ? clsAb[u & 1] : clsBb[u & 1];
        const bool offdiag = !diag;

        int ca[16];
        #pragma unroll
        for (int fa = 0; fa < 4; ++fa)
            #pragma unroll
            for (int j = 0; j < 4; ++j) ca[fa * 4 + j] = clsA_[li_base + fa * 16 + j];

        #pragma unroll
        for (int fb = 0; fb < 4; ++fb) {
            const int lj = lj_base + fb * 16;
            const int cb = clsB_[lj];
            #pragma unroll
            for (int fa = 0; fa < 4; ++fa) {
                const int li0 = li_base + fa * 16;
                f32x4 v = acc[fa][fb];
                #pragma unroll
                for (int j = 0; j < 4; ++j) {
                    const int li = li0 + j;
                    const bool mneg = (offdiag || (li < lj)) && (ca[fa * 4 + j] != cb);
                    float s = v[j];
                    s = fminf(fmaxf(s, -CLIPV), CLIPV);
                    float uu = (s + CLIPV) * INVSTEP;
                    int jb = (int)uu;
                    if (jb > 98) jb = 98;
                    float w_hi = uu - (float)jb;
                    float2 cd = crep2[jb];
                    float mm = mneg ? 1.0f : 0.0f;
                    lacc = fmaf(mm, fmaf(w_hi, cd.y, cd.x), lacc);
                    lcnt += mm;
                }
            }
        }
    }
    #undef STAGE_UNIT

    // reduce: wave shuffle -> 4 partials -> 2 atomics into 32 slots
    #pragma unroll
    for (int off = 32; off > 0; off >>= 1) {
        lacc += __shfl_xor(lacc, off);
        lcnt += __shfl_xor(lcnt, off);
    }
    if (lane == 0) { red[wid] = lacc; red[4 + wid] = lcnt; }
    __syncthreads();
    if (tid == 0) {
        float L = red[0] + red[1] + red[2] + red[3];
        float C = red[4] + red[5] + red[6] + red[7];
        faddf(&gLoss[blockIdx.x & 31], L);
        faddf(&gCnt[blockIdx.x & 31], C);
        __threadfence();
        unsigned int tk = atomicAdd(gDone, 1u);
        if (tk == NBLK - 1) {
            __threadfence();
            float ls = 0.f, cs = 0.f;
            for (int i = 0; i < 32; ++i) {
                ls += __hip_atomic_load(&gLoss[i], __ATOMIC_RELAXED, __HIP_MEMORY_SCOPE_AGENT);
                cs += __hip_atomic_load(&gCnt[i], __ATOMIC_RELAXED, __HIP_MEMORY_SCOPE_AGENT);
            }
            out[0] = ls / cs;            // cdf already contains 1/sp
        }
    }
}

extern "C" void kernel_launch(void* const* d_in, const int* in_sizes, int n_in,
                              void* d_out, int out_size, void* d_ws, size_t ws_size,
                              hipStream_t stream) {
    const float* emb = (const float*)d_in[0];
    const int* classes = (const int*)d_in[1];
    float* out = (float*)d_out;

    ushort* nemb = (ushort*)d_ws;                                   // 1 MB
    float* ctl = (float*)((char*)d_ws + (size_t)BN * DD * sizeof(ushort));
    float* gPos = ctl;                                // 100
    float* gLoss = gPos + NSTEPS;                     // 32
    float* gCnt = gLoss + 32;                         // 32
    unsigned int* gDone = (unsigned int*)(gCnt + 32); // 1
    unsigned int* gDoneP = gDone + 1;                 // 1
    float* gCdf = (float*)(gDoneP + 1);               // 100 (fully written)

    hl_normalize<<<BN / 4, 256, 0, stream>>>(emb, nemb, ctl);
    hl_poscls<<<NSTEPS, 256, 0, stream>>>(nemb, classes, gPos, gDoneP, gCdf);
    hl_neg<<<NBLK, 256, 0, stream>>>(nemb, classes, gCdf, gLoss, gCnt, gDone, out);
}